// Round 1
// baseline (134.703 us; speedup 1.0000x reference)
//
#include <hip/hip_runtime.h>

// out[n,c,p,y,x] = in1[n,c,y,x] - zpad(in2)[n,c, y+i-3, x+j-3],  p = i*7+j
// N=8, C=32, H=W=112, K=7, pad=3, stride=dil=1  -> out [8,32,49,112,112] fp32
//
// Write-BW-bound: 629 MB output, 25.7 MB inputs (L2-resident).
// One thread per (nc, y, x4): 1 float4 in1 load, 7x10 in2 window loads,
// 49 coalesced float4 stores.

#define NC_TOT   256        // 8*32
#define HW       112
#define PLANE    12544      // 112*112
#define X4       28         // 112/4
#define THREADS_TOT (NC_TOT * HW * X4)   // 802816

__global__ __launch_bounds__(256) void sub2_kernel(
    const float* __restrict__ in1,
    const float* __restrict__ in2,
    float* __restrict__ out)
{
    int t = blockIdx.x * blockDim.x + threadIdx.x;
    if (t >= THREADS_TOT) return;

    int x4 = t % X4;
    int ry = t / X4;
    int y  = ry % HW;
    int nc = ry / HW;
    int x0 = x4 * 4;

    // center values (reused for all 49 outputs)
    const float4 a = *reinterpret_cast<const float4*>(
        in1 + (size_t)(nc * HW + y) * HW + x0);

    const float* b2 = in2 + (size_t)nc * PLANE;
    float* po = out + (size_t)nc * 49 * PLANE + (size_t)y * HW + x0;

    #pragma unroll
    for (int i = 0; i < 7; ++i) {
        int iy = y + i - 3;
        float w[10];
        if (iy >= 0 && iy < HW) {
            const float* pr = b2 + iy * HW;
            #pragma unroll
            for (int m = 0; m < 10; ++m) {
                int wx = x0 - 3 + m;
                w[m] = (wx >= 0 && wx < HW) ? pr[wx] : 0.0f;
            }
        } else {
            #pragma unroll
            for (int m = 0; m < 10; ++m) w[m] = 0.0f;
        }
        #pragma unroll
        for (int j = 0; j < 7; ++j) {
            float4 r;
            r.x = a.x - w[j + 0];
            r.y = a.y - w[j + 1];
            r.z = a.z - w[j + 2];
            r.w = a.w - w[j + 3];
            *reinterpret_cast<float4*>(po + (size_t)(i * 7 + j) * PLANE) = r;
        }
    }
}

extern "C" void kernel_launch(void* const* d_in, const int* in_sizes, int n_in,
                              void* d_out, int out_size, void* d_ws, size_t ws_size,
                              hipStream_t stream) {
    const float* in1 = (const float*)d_in[0];
    const float* in2 = (const float*)d_in[1];
    float* out = (float*)d_out;

    const int threads = 256;
    const int blocks = (THREADS_TOT + threads - 1) / threads;  // 3136
    sub2_kernel<<<blocks, threads, 0, stream>>>(in1, in2, out);
}